// Round 3
// baseline (416.499 us; speedup 1.0000x reference)
//
#include <hip/hip_runtime.h>

// Problem constants (from reference setup_inputs / NUM_DISPARITIES)
constexpr int B = 2, C = 32, H = 136, W = 240, D = 48;
constexpr int W4     = W / 4;          // 60 float4 per row
constexpr int PLANE  = H * W;          // 32640 elements per (b,c,d) plane
constexpr int RROWS  = 17;             // rows per block (136 = 8*17)
constexpr int HCH    = H / RROWS;      // 8 row-chunks
constexpr int NBLK   = B * C * HCH;    // 512 blocks
constexpr int LDS_ROW4 = 76;           // float4 stride per LDS row (304 floats)
constexpr float CLAMPV = 1000.0f;

typedef float v4f __attribute__((ext_vector_type(4)));

__device__ __forceinline__ float clampv(float x) {
    return fminf(CLAMPV, fmaxf(-CLAMPV, x));
}

// LDS row layout (floats): [0..63] zero pad (implements w<d masking for free),
// [64..303] the 240 floats of one right row. Row stride 304 floats (1216 B,
// 16B-aligned) -> all windowed reads below are aligned ds_read_b128 with
// r*1216 as the offset immediate.
//
// Wave w owns disparities d = 8k + w, k = 0..5. Since d = w (mod 4), the
// sliding-window extraction pattern is COMPILE-TIME per wave (template A=w&3):
// window [s..s+3] with s = 64-d+4*lane is covered by aligned X (at s-M,
// M=(4-A)&3) and Y=X+4:
//   A=0: [X0 X1 X2 X3]   A=1: [X3 Y0 Y1 Y2]
//   A=2: [X2 X3 Y0 Y1]   A=3: [X1 X2 X3 Y0]
// For each d the wave streams ALL 17 rows in address order -> each (wave,d)
// store stream is one 16.3 KB CONTIGUOUS run (DRAM row-buffer friendly),
// instead of round-1's 48-way-scattered 960 B chunks.
template<int A>
__device__ __forceinline__ void compute_wave(
        const float* __restrict__ srow, int lane, int w, int bc, int h0,
        const float* __restrict__ lbase, float* __restrict__ out) {
    constexpr int M = (4 - A) & 3;
    #pragma unroll
    for (int k = 0; k < 6; ++k) {
        const int d = 8 * k + w;
        const v4f* __restrict__ px =
            (const v4f*)srow + ((64 - d - M + 4 * lane) >> 2);
        float* __restrict__ obase =
            out + (size_t)(bc * D + d) * PLANE + (size_t)h0 * W + 4 * lane;
        #pragma unroll 4
        for (int r = 0; r < RROWS; ++r) {
            const v4f X = px[r * LDS_ROW4];
            v4f Y = X;
            if constexpr (A != 0) Y = px[r * LDS_ROW4 + 1];
            const v4f l4 = *(const v4f*)(lbase + r * W);   // L1-cached re-read
            float win[4];
            #pragma unroll
            for (int e = 0; e < 4; ++e) {
                const int idx = M + e;                      // static after unroll
                win[e] = (idx < 4) ? X[idx] : Y[idx - 4];
            }
            v4f o;
            o.x = clampv(l4.x * win[0]);
            o.y = clampv(l4.y * win[1]);
            o.z = clampv(l4.z * win[2]);
            o.w = clampv(l4.w * win[3]);
            __builtin_nontemporal_store(o, (v4f*)(obase + r * W));
        }
    }
}

__global__ __launch_bounds__(512) void CostVolume_4939212390829_kernel(
        const float* __restrict__ left,
        const float* __restrict__ right,
        float* __restrict__ out) {
    const int blk = blockIdx.x;
    const int bc  = blk / HCH;
    const int h0  = (blk - bc * HCH) * RROWS;
    const int tid = threadIdx.x;

    __shared__ v4f sR[RROWS * LDS_ROW4];    // 20,672 B -> 2 blocks/CU easily

    // zero the 64-float left pads (17 rows x 16 float4)
    for (int i = tid; i < RROWS * 16; i += 512) {
        const int r = i >> 4, c = i & 15;
        sR[r * LDS_ROW4 + c] = (v4f){0.f, 0.f, 0.f, 0.f};
    }
    // stage the 17 right rows (coalesced float4 loads)
    const float* __restrict__ rbase = right + (size_t)bc * PLANE + (size_t)h0 * W;
    for (int i = tid; i < RROWS * W4; i += 512) {
        const int r = i / W4, c = i - r * W4;
        sR[r * LDS_ROW4 + 16 + c] = *(const v4f*)(rbase + r * W + 4 * c);
    }
    __syncthreads();

    const int w    = tid >> 6;     // wave id 0..7
    const int lane = tid & 63;
    if (lane >= W4) return;        // lanes 60..63 idle in compute

    const float* __restrict__ lbase =
        left + (size_t)bc * PLANE + (size_t)h0 * W + 4 * lane;
    const float* __restrict__ srow = (const float*)sR;

    switch (w & 3) {
        case 0: compute_wave<0>(srow, lane, w, bc, h0, lbase, out); break;
        case 1: compute_wave<1>(srow, lane, w, bc, h0, lbase, out); break;
        case 2: compute_wave<2>(srow, lane, w, bc, h0, lbase, out); break;
        case 3: compute_wave<3>(srow, lane, w, bc, h0, lbase, out); break;
    }
}

extern "C" void kernel_launch(void* const* d_in, const int* in_sizes, int n_in,
                              void* d_out, int out_size, void* d_ws, size_t ws_size,
                              hipStream_t stream) {
    const float* left  = (const float*)d_in[0];
    const float* right = (const float*)d_in[1];
    float* out = (float*)d_out;
    (void)in_sizes; (void)n_in; (void)out_size; (void)d_ws; (void)ws_size;

    CostVolume_4939212390829_kernel<<<NBLK, 512, 0, stream>>>(left, right, out);
}

// Round 4
// 406.504 us; speedup vs baseline: 1.0246x; 1.0246x over previous
//
#include <hip/hip_runtime.h>

// Problem constants (from reference setup_inputs / NUM_DISPARITIES)
constexpr int B = 2, C = 32, H = 136, W = 240, D = 48;
constexpr int W4     = W / 4;          // 60 float4 per row
constexpr int PLANE  = H * W;          // 32640 elements per (b,c,d) plane
constexpr int ROWS   = 4;              // rows per block (one per wave)
constexpr int HCHUNK = H / ROWS;       // 34 row-chunks
constexpr int NBLK   = B * C * HCHUNK; // 2176 blocks
constexpr float CLAMPV = 1000.0f;

// LDS row layout (floats): [0..63] zero pad (implements w<d masking for free),
// [64..303] the 240 floats of one right row, [304..311] slack. 312*4B = 1248 B,
// 16B-aligned so every windowed read below is a ds_read_b128.
constexpr int LROW = 312;

typedef float v4f __attribute__((ext_vector_type(4)));

__device__ __forceinline__ float clampv(float x) {
    return fminf(CLAMPV, fmaxf(-CLAMPV, x));  // -> v_med3_f32
}

// Block = (bc, 4-row chunk). Wave g owns row h0+g: stages the right row into
// its private LDS row ONCE (zero-padded left edge), keeps left float4 in regs,
// then produces all 48 disparity outputs for its 60 float4 columns.
// For 4 consecutive disparities d = 4q..4q+3, the 4 sliding windows
// right[4*lane-d .. +3] are covered by two adjacent 16B LDS reads X,Y —
// extraction is pure compile-time register renaming. No compares, no masks,
// no division, no barrier (each wave touches only its own LDS row).
//
// Round-3 A/B: NT stores w/ scattered 960B chunks = 148 µs; NT stores w/
// 16.3 KB contiguous runs = 159 µs -> address pattern is NOT the limiter.
// This round: plain stores (L2 writeback path, like the 6.4 TB/s fill)
// instead of __builtin_nontemporal_store (suspected ~2.7 TB/s nt path).
__global__ __launch_bounds__(256) void CostVolume_4939212390829_kernel(
        const float* __restrict__ left,
        const float* __restrict__ right,
        float* __restrict__ out) {
    const int blk  = blockIdx.x;
    const int bc   = blk / HCHUNK;
    const int h0   = (blk - bc * HCHUNK) * ROWS;
    const int g    = threadIdx.x >> 6;    // wave id = row within chunk
    const int lane = threadIdx.x & 63;
    const int h    = h0 + g;

    __shared__ v4f lds_v[ROWS * (LROW / 4)];   // v4f-typed -> 16B aligned
    float* lrow = reinterpret_cast<float*>(lds_v) + g * LROW;

    const size_t inoff = (size_t)bc * PLANE + (size_t)h * W;

    // zero the 64-float left pad (lanes 0..15, 16B each)
    if (lane < 16) {
        v4f z = {0.0f, 0.0f, 0.0f, 0.0f};
        *reinterpret_cast<v4f*>(lrow + 4 * lane) = z;
    }

    v4f l4 = {0.0f, 0.0f, 0.0f, 0.0f};
    if (lane < W4) {
        // stage right row into LDS floats [64..303]; left stays in registers
        *reinterpret_cast<v4f*>(lrow + 64 + 4 * lane) =
            *reinterpret_cast<const v4f*>(right + inoff + 4 * lane);
        l4 = *reinterpret_cast<const v4f*>(left + inoff + 4 * lane);
    }

    if (lane >= W4) return;   // no barrier anywhere: LDS rows are wave-private

    // X window base for q=0: row float 60 + 4*lane  (= data index 4*lane - 4)
    const float* px0 = lrow + 60 + 4 * lane;
    // output element index for d=0 at this (h, w): fits u32 (max ~100M)
    const uint32_t obase = (uint32_t)(bc * D) * PLANE + (uint32_t)h * W + 4 * lane;

    for (int q = 0; q < D / 4; ++q) {
        const float* px = px0 - 4 * q;
        const v4f X = *reinterpret_cast<const v4f*>(px);       // data[4l-4q-4 ..]
        const v4f Y = *reinterpret_cast<const v4f*>(px + 4);   // data[4l-4q   ..]
        const uint32_t o0 = obase + (uint32_t)(4 * q) * PLANE;

        v4f o;
        // d = 4q
        o.x = clampv(l4.x * Y.x); o.y = clampv(l4.y * Y.y);
        o.z = clampv(l4.z * Y.z); o.w = clampv(l4.w * Y.w);
        *reinterpret_cast<v4f*>(out + o0) = o;
        // d = 4q+1
        o.x = clampv(l4.x * X.w); o.y = clampv(l4.y * Y.x);
        o.z = clampv(l4.z * Y.y); o.w = clampv(l4.w * Y.z);
        *reinterpret_cast<v4f*>(out + o0 + PLANE) = o;
        // d = 4q+2
        o.x = clampv(l4.x * X.z); o.y = clampv(l4.y * X.w);
        o.z = clampv(l4.z * Y.x); o.w = clampv(l4.w * Y.y);
        *reinterpret_cast<v4f*>(out + o0 + 2 * PLANE) = o;
        // d = 4q+3
        o.x = clampv(l4.x * X.y); o.y = clampv(l4.y * X.z);
        o.z = clampv(l4.z * X.w); o.w = clampv(l4.w * Y.x);
        *reinterpret_cast<v4f*>(out + o0 + 3 * PLANE) = o;
    }
}

extern "C" void kernel_launch(void* const* d_in, const int* in_sizes, int n_in,
                              void* d_out, int out_size, void* d_ws, size_t ws_size,
                              hipStream_t stream) {
    const float* left  = (const float*)d_in[0];
    const float* right = (const float*)d_in[1];
    float* out = (float*)d_out;
    (void)in_sizes; (void)n_in; (void)out_size; (void)d_ws; (void)ws_size;

    CostVolume_4939212390829_kernel<<<NBLK, 256, 0, stream>>>(left, right, out);
}